// Round 5
// baseline (1076.037 us; speedup 1.0000x reference)
//
#include <hip/hip_runtime.h>

// Problem constants (from reference)
constexpr int BATCH = 16384;
constexpr int NN    = 4096;    // NUM_NEURONS
constexpr int BS    = 32;      // BLOCK_SIZE
constexpr int NB    = NN / BS; // 128 blocks

constexpr int THREADS     = 256;   // 4 waves
constexpr int ROWS_PER_WG = 512;
constexpr int ROWS_PER_IT = 32;    // 4 waves x 8 rows
constexpr int ITERS       = ROWS_PER_WG / ROWS_PER_IT; // 16

typedef float f32x4 __attribute__((ext_vector_type(4)));
typedef float f32x2 __attribute__((ext_vector_type(2)));

// Lane layout within a wave: r = lane>>3 (owned row in 8-row slab), g = lane&7
// (owned column float4-quad). EVERY lane holds the full 128-B v-row of row r
// in registers (8 f32x4 loads; addresses depend only on r -> 8 distinct 16-B
// segments per instruction, broadcast to the 8 column-group lanes). v[k] is a
// compile-time register access -> NO cross-lane ops in the k-loop.
//
// Per k-step: one conflict-free ds_read_b128 of A[k][4g..4g+3] (banks 4g+e
// span all 32 exactly once, 8-way broadcast over r) + 4 FMAs.
template <int K>
struct KStep {
    static __device__ __forceinline__ void run(const f32x4* __restrict__ w,
                                               const f32x4* __restrict__ Alds,
                                               int g, float* __restrict__ acc) {
        constexpr int j = K >> 2;   // which f32x4 of the row
        constexpr int e = K & 3;    // which component
        const float vk = w[j][e];
        const f32x4 a = Alds[K * 8 + g];
        acc[0] = fmaf(vk, a.x, acc[0]);
        acc[1] = fmaf(vk, a.y, acc[1]);
        acc[2] = fmaf(vk, a.z, acc[2]);
        acc[3] = fmaf(vk, a.w, acc[3]);
        KStep<K + 1>::run(w, Alds, g, acc);
    }
};
template <>
struct KStep<BS> {
    static __device__ __forceinline__ void run(const f32x4* __restrict__,
                                               const f32x4* __restrict__,
                                               int, float* __restrict__) {}
};

__global__ __launch_bounds__(THREADS, 8) void tn_kernel(
    const float* __restrict__ v,
    const float* __restrict__ dx,
    const float* __restrict__ A,
    const float* __restrict__ Bm,
    const float* __restrict__ bsc,
    float* __restrict__ out)
{
    __shared__ f32x4 Alds[BS * BS / 4]; // A[k][l], l fastest (256 x float4)

    const int tid  = threadIdx.x;
    const int nblk = blockIdx.x & (NB - 1);
    const int rt   = blockIdx.x >> 7;

    // Stage A[nblk] (4 KB): 256 threads x one float4
    Alds[tid] = reinterpret_cast<const f32x4*>(A + nblk * (BS * BS))[tid];
    __syncthreads();

    const float bias = *bsc;
    const int lane = tid & 63;
    const int wv   = tid >> 6;
    const int r    = lane >> 3;
    const int g    = lane & 7;

    // B rows for this lane's 4 output columns (8 contiguous floats, L2-hot).
    const f32x4* Bp = reinterpret_cast<const f32x4*>(Bm + nblk * (BS * 2) + g * 8);
    const f32x4 B0 = Bp[0];  // {B[c0][0],B[c0][1],B[c1][0],B[c1][1]}
    const f32x4 B1 = Bp[1];  // {B[c2][0],B[c2][1],B[c3][0],B[c3][1]}

    int row = rt * ROWS_PER_WG + wv * 8 + r;
    size_t rbase = (size_t)row * NN + nblk * BS;       // row-slice base (no g)
    constexpr size_t IT_STRIDE = (size_t)ROWS_PER_IT * NN;

#pragma unroll 1
    for (int it = 0; it < ITERS; ++it) {
        // Full 128-B row slice into registers (cached loads: 8 instrs/line,
        // line fetched once, fully consumed immediately).
        f32x4 w[8];
        const f32x4* vp = reinterpret_cast<const f32x4*>(v + rbase);
#pragma unroll
        for (int j = 0; j < 8; ++j) w[j] = vp[j];

        const f32x2 dd = *reinterpret_cast<const f32x2*>(dx + (size_t)row * 2);

        float acc[4] = {0.f, 0.f, 0.f, 0.f};
        KStep<0>::run(w, Alds, g, acc);

        f32x4 o;
        o.x = fmaxf(fmaf(dd.x, B0.x, fmaf(dd.y, B0.y, acc[0] + bias)), 0.f);
        o.y = fmaxf(fmaf(dd.x, B0.z, fmaf(dd.y, B0.w, acc[1] + bias)), 0.f);
        o.z = fmaxf(fmaf(dd.x, B1.x, fmaf(dd.y, B1.y, acc[2] + bias)), 0.f);
        o.w = fmaxf(fmaf(dd.x, B1.z, fmaf(dd.y, B1.w, acc[3] + bias)), 0.f);
        // Store: lane(r,g) writes 16 B; one instruction covers 8 full lines.
        __builtin_nontemporal_store(
            o, reinterpret_cast<f32x4*>(out + rbase + g * 4));

        row   += ROWS_PER_IT;
        rbase += IT_STRIDE;
    }
}

extern "C" void kernel_launch(void* const* d_in, const int* in_sizes, int n_in,
                              void* d_out, int out_size, void* d_ws, size_t ws_size,
                              hipStream_t stream) {
    const float* v  = (const float*)d_in[0];  // [16384,4096]
    const float* dx = (const float*)d_in[1];  // [16384,2]
    const float* A  = (const float*)d_in[2];  // [128,32,32]
    const float* Bm = (const float*)d_in[3];  // [4096,2]
    const float* b  = (const float*)d_in[4];  // scalar
    float* out = (float*)d_out;               // [16384,4096]

    const int grid = NB * (BATCH / ROWS_PER_WG); // 128 * 32 = 4096
    tn_kernel<<<dim3(grid), dim3(THREADS), 0, stream>>>(v, dx, A, Bm, b, out);
}

// Round 6
// 115.458 us; speedup vs baseline: 9.3197x; 9.3197x over previous
//
#include <hip/hip_runtime.h>

// Problem constants (from reference)
constexpr int BATCH = 16384;
constexpr int NN    = 4096;    // NUM_NEURONS
constexpr int BS    = 32;      // BLOCK_SIZE
constexpr int NB    = NN / BS; // 128 blocks

constexpr int THREADS     = 256;   // 4 waves
constexpr int ROWS_PER_WG = 512;
constexpr int ROWS_PER_IT = 64;    // 4 waves x 16 rows
constexpr int ITERS       = ROWS_PER_WG / ROWS_PER_IT; // 8

typedef float f32x4 __attribute__((ext_vector_type(4)));
typedef float f32x2 __attribute__((ext_vector_type(2)));

// Lane layout: r = lane>>2 (row, 16 rows/wave), q = lane&3. Each lane owns
// 8 output columns {4q..4q+3, 16+4q..16+4q+3} and holds the matching v
// elements w[0]=v[row,4q..4q+3], w[1]=v[row,16+4q..16+4q+3].
//
// v[row,k] broadcast: the owner of k is lane (k>>2)&3 WITHIN THE QUAD ->
// quad_perm DPP broadcast on the VALU pipe, zero DS-pipe traffic.
// Per k-step: 2 conflict-free ds_read_b128 of A[k] (addresses depend only on
// q: 4/4 distinct 16-B chunks per read, 16-way broadcast over r) + 8 FMAs.
// DS instructions per row: 4 (vs 8 in the swizzle version).

template <int S>
__device__ __forceinline__ float qbcast(float x) {
    // quad_perm [S,S,S,S]; bound_ctrl irrelevant (all lanes active)
    return __int_as_float(__builtin_amdgcn_update_dpp(
        0, __float_as_int(x), S * 0x55, 0xF, 0xF, true));
}

template <int K>
struct KStep {
    static __device__ __forceinline__ void run(const f32x4* __restrict__ w,
                                               const float* __restrict__ Alds,
                                               int q, float* __restrict__ acc) {
        constexpr int s = (K >> 2) & 3;  // owner lane within quad
        constexpr int h = K >> 4;        // which w register
        constexpr int e = K & 3;         // component
        const float vk = qbcast<s>(w[h][e]);
        const f32x4 a0 = *reinterpret_cast<const f32x4*>(Alds + K * BS + q * 4);
        const f32x4 a1 = *reinterpret_cast<const f32x4*>(Alds + K * BS + q * 4 + 16);
        acc[0] = fmaf(vk, a0.x, acc[0]);
        acc[1] = fmaf(vk, a0.y, acc[1]);
        acc[2] = fmaf(vk, a0.z, acc[2]);
        acc[3] = fmaf(vk, a0.w, acc[3]);
        acc[4] = fmaf(vk, a1.x, acc[4]);
        acc[5] = fmaf(vk, a1.y, acc[5]);
        acc[6] = fmaf(vk, a1.z, acc[6]);
        acc[7] = fmaf(vk, a1.w, acc[7]);
        KStep<K + 1>::run(w, Alds, q, acc);
    }
};
template <>
struct KStep<BS> {
    static __device__ __forceinline__ void run(const f32x4* __restrict__,
                                               const float* __restrict__,
                                               int, float* __restrict__) {}
};

__global__ __launch_bounds__(THREADS) void tn_kernel(
    const float* __restrict__ v,
    const float* __restrict__ dx,
    const float* __restrict__ A,
    const float* __restrict__ Bm,
    const float* __restrict__ bsc,
    float* __restrict__ out)
{
    __shared__ float Alds[BS * BS]; // A[k][l], l fastest

    const int tid  = threadIdx.x;
    const int nblk = blockIdx.x & (NB - 1);
    const int rt   = blockIdx.x >> 7;

    // Stage A[nblk] (4 KB): 256 threads x one float4
    reinterpret_cast<f32x4*>(Alds)[tid] =
        reinterpret_cast<const f32x4*>(A + nblk * (BS * BS))[tid];
    __syncthreads();

    const float bias = *bsc;
    const int lane = tid & 63;
    const int wv   = tid >> 6;
    const int r    = lane >> 2;
    const int q    = lane & 3;

    // B entries for this lane's 8 output columns (L2-hot, 32 KB total).
    const float* Bb = Bm + nblk * (BS * 2);
    const f32x4 B0a = *reinterpret_cast<const f32x4*>(Bb + q * 8);          // cols 4q,4q+1
    const f32x4 B0b = *reinterpret_cast<const f32x4*>(Bb + q * 8 + 4);      // cols 4q+2,4q+3
    const f32x4 B1a = *reinterpret_cast<const f32x4*>(Bb + 32 + q * 8);     // cols 16+4q..
    const f32x4 B1b = *reinterpret_cast<const f32x4*>(Bb + 32 + q * 8 + 4);

    int row = rt * ROWS_PER_WG + wv * 16 + r;
    size_t rbase = (size_t)row * NN + nblk * BS;
    constexpr size_t IT_STRIDE = (size_t)ROWS_PER_IT * NN;

    // Software pipeline: prefetch next iteration's v/dx while computing.
    f32x4 w[2];
    w[0] = *reinterpret_cast<const f32x4*>(v + rbase + q * 4);
    w[1] = *reinterpret_cast<const f32x4*>(v + rbase + q * 4 + 16);
    f32x2 dd = *reinterpret_cast<const f32x2*>(dx + (size_t)row * 2);

#pragma unroll 1
    for (int it = 0; it < ITERS; ++it) {
        f32x4 wn[2];
        f32x2 ddn;
        if (it < ITERS - 1) {
            wn[0] = *reinterpret_cast<const f32x4*>(v + rbase + IT_STRIDE + q * 4);
            wn[1] = *reinterpret_cast<const f32x4*>(v + rbase + IT_STRIDE + q * 4 + 16);
            ddn   = *reinterpret_cast<const f32x2*>(dx + (size_t)(row + ROWS_PER_IT) * 2);
        } else {
            wn[0] = w[0]; wn[1] = w[1]; ddn = dd;
        }

        float acc[8] = {};
        KStep<0>::run(w, Alds, q, acc);

        f32x4 o0, o1;
        o0.x = fmaxf(fmaf(dd.x, B0a.x, fmaf(dd.y, B0a.y, acc[0] + bias)), 0.f);
        o0.y = fmaxf(fmaf(dd.x, B0a.z, fmaf(dd.y, B0a.w, acc[1] + bias)), 0.f);
        o0.z = fmaxf(fmaf(dd.x, B0b.x, fmaf(dd.y, B0b.y, acc[2] + bias)), 0.f);
        o0.w = fmaxf(fmaf(dd.x, B0b.z, fmaf(dd.y, B0b.w, acc[3] + bias)), 0.f);
        o1.x = fmaxf(fmaf(dd.x, B1a.x, fmaf(dd.y, B1a.y, acc[4] + bias)), 0.f);
        o1.y = fmaxf(fmaf(dd.x, B1a.z, fmaf(dd.y, B1a.w, acc[5] + bias)), 0.f);
        o1.z = fmaxf(fmaf(dd.x, B1b.x, fmaf(dd.y, B1b.y, acc[6] + bias)), 0.f);
        o1.w = fmaxf(fmaf(dd.x, B1b.z, fmaf(dd.y, B1b.w, acc[7] + bias)), 0.f);

        // Stores: per instr, each quad writes a 64-B aligned 64-B chunk;
        // the two instrs complete each 128-B line within the same wave.
        __builtin_nontemporal_store(o0, reinterpret_cast<f32x4*>(out + rbase + q * 4));
        __builtin_nontemporal_store(o1, reinterpret_cast<f32x4*>(out + rbase + q * 4 + 16));

        w[0] = wn[0]; w[1] = wn[1]; dd = ddn;
        row   += ROWS_PER_IT;
        rbase += IT_STRIDE;
    }
}

extern "C" void kernel_launch(void* const* d_in, const int* in_sizes, int n_in,
                              void* d_out, int out_size, void* d_ws, size_t ws_size,
                              hipStream_t stream) {
    const float* v  = (const float*)d_in[0];  // [16384,4096]
    const float* dx = (const float*)d_in[1];  // [16384,2]
    const float* A  = (const float*)d_in[2];  // [128,32,32]
    const float* Bm = (const float*)d_in[3];  // [4096,2]
    const float* b  = (const float*)d_in[4];  // scalar
    float* out = (float*)d_out;               // [16384,4096]

    const int grid = NB * (BATCH / ROWS_PER_WG); // 128 * 32 = 4096
    tn_kernel<<<dim3(grid), dim3(THREADS), 0, stream>>>(v, dx, A, Bm, b, out);
}